// Round 3
// baseline (384.711 us; speedup 1.0000x reference)
//
#include <hip/hip_runtime.h>
#include <hip/hip_bf16.h>
#include <math.h>

#define B 4
#define C 256
#define H 256
#define Wd 256

// ---------------------------------------------------------------------------
// K1: barrier-free single pass over x. Per (b,c) plane produces:
//   pool16 (16x16 patch means), xproj16/8/4 (interp-transpose projections),
//   sx = (sum x, sum x^2).
// Wave wg owns rows [64wg,64wg+64); 64-row loop fully unrolled so all
// accumulator indices are compile-time. Lane l owns pixels [4l,4l+4): each
// lane has a single w-segment lo per scale, contribution (p0-S, S) with
// S = alpha*p0 + beta*pw (affine frac). One barrier + LDS merge at the end.
// ---------------------------------------------------------------------------
__global__ __launch_bounds__(256) void poolproj_kernel(
    const float* __restrict__ x,
    float* __restrict__ pool16, float* __restrict__ xp16o,
    float* __restrict__ xp8o, float* __restrict__ xp4o,
    float* __restrict__ sx) {

    __shared__ float M[256][33];

    int bc = blockIdx.x;
    int t = threadIdx.x;
    int wg = t >> 6, l = t & 63;
    bool clipLo = (wg == 0), clipHi = (wg == 3);

    const float4* xp = (const float4*)(x + (size_t)bc * (H * Wd));

    // per-lane w-side constants (alpha, beta of S = alpha*p0 + beta*pw)
    float a16, b16, a8, b8, a4, b4;
    {
        float w0 = 4.f * (float)l + 0.5f;
        float s16v = w0 * 0.0625f - 0.5f;
        if (l <= 1 || l >= 62) { a16 = 0.f; b16 = 0.f; }
        else { a16 = s16v - floorf(s16v); b16 = 0.0625f; }
        float s8v = w0 * 0.03125f - 0.5f;
        if (l <= 3 || l >= 60) { a8 = 0.f; b8 = 0.f; }
        else { a8 = s8v - floorf(s8v); b8 = 0.03125f; }
        float s4v = w0 * 0.015625f - 0.5f;
        if (l <= 7 || l >= 56) { a4 = 0.f; b4 = 0.f; }
        else { a4 = s4v - floorf(s4v); b4 = 0.015625f; }
    }

    float A16L[6] = {0,0,0,0,0,0}, A16H[6] = {0,0,0,0,0,0};
    float A8L[4] = {0,0,0,0},      A8H[4] = {0,0,0,0};
    float A4L[3] = {0,0,0},        A4H[3] = {0,0,0};
    float PP[4] = {0,0,0,0};
    float sx1 = 0.f, sx2 = 0.f;

#pragma unroll 64
    for (int rr = 0; rr < 64; ++rr) {
        float4 v = xp[((wg << 6) + rr) * 64 + l];
        float p0 = (v.x + v.y) + (v.z + v.w);
        float pw = fmaf(3.f, v.w, fmaf(2.f, v.z, v.y));   // sum p*x_p (local)
        sx1 += p0;
        sx2 += v.x * v.x + v.y * v.y + v.z * v.z + v.w * v.w;
        PP[rr >> 4] += p0;

        float S16 = fmaf(b16, pw, a16 * p0);
        float S8  = fmaf(b8,  pw, a8  * p0);
        float S4  = fmaf(b4,  pw, a4  * p0);
        float u16 = p0 - S16, u8 = p0 - S8, u4 = p0 - S4;

        // s16 h-weights (compile-time for interior rows)
        {
            const float c = ((float)rr + 0.5f) * 0.0625f - 0.5f;
            const int lor = (rr >= 8) ? ((rr - 8) >> 4) : -1;
            const float fh = c - (float)lor;
            float wlo = 1.f - fh, whi = fh;
            if (rr < 8)   { if (clipLo) { wlo = 0.f; whi = 1.f; } }
            if (rr >= 56) { if (clipHi) { wlo = 1.f; whi = 0.f; } }
            A16L[lor + 1] += wlo * u16;  A16L[lor + 2] += whi * u16;
            A16H[lor + 1] += wlo * S16;  A16H[lor + 2] += whi * S16;
        }
        // s8
        {
            const float c = ((float)rr + 0.5f) * 0.03125f - 0.5f;
            const int lor = (rr >= 16) ? ((rr - 16) >> 5) : -1;
            const float fh = c - (float)lor;
            float wlo = 1.f - fh, whi = fh;
            if (rr < 16)  { if (clipLo) { wlo = 0.f; whi = 1.f; } }
            if (rr >= 48) { if (clipHi) { wlo = 1.f; whi = 0.f; } }
            A8L[lor + 1] += wlo * u8;  A8L[lor + 2] += whi * u8;
            A8H[lor + 1] += wlo * S8;  A8H[lor + 2] += whi * S8;
        }
        // s4
        {
            const float c = ((float)rr + 0.5f) * 0.015625f - 0.5f;
            const int lor = (rr >= 32) ? 0 : -1;
            const float fh = c - (float)lor;
            float wlo = 1.f - fh, whi = fh;
            if (rr < 32)  { if (clipLo) { wlo = 0.f; whi = 1.f; } }
            if (rr >= 32) { if (clipHi) { wlo = 1.f; whi = 0.f; } }
            A4L[lor + 1] += wlo * u4;  A4L[lor + 2] += whi * u4;
            A4H[lor + 1] += wlo * S4;  A4H[lor + 2] += whi * S4;
        }
    }

    // dump accumulators to LDS
    {
        float* m = M[t];
#pragma unroll
        for (int q = 0; q < 6; ++q) { m[q] = A16L[q]; m[6 + q] = A16H[q]; }
#pragma unroll
        for (int q = 0; q < 4; ++q) { m[12 + q] = A8L[q]; m[16 + q] = A8H[q]; }
#pragma unroll
        for (int q = 0; q < 3; ++q) { m[20 + q] = A4L[q]; m[23 + q] = A4H[q]; }
#pragma unroll
        for (int q = 0; q < 4; ++q) m[26 + q] = PP[q];
        m[30] = sx1; m[31] = sx2;
    }
    __syncthreads();

    // ---- deterministic merge ----
    // xproj16: thread t -> (i = t>>4, j = t&15)
    {
        int i = t >> 4, j = t & 15;
        float sum = 0.f;
        for (int w2 = 0; w2 < 4; ++w2) {
            int idx = i - 4 * w2 + 1;
            if (idx < 0 || idx > 5) continue;
            int lbeg = (j == 0) ? 0 : 4 * j + 2;
            int lend = (j == 15) ? 64 : 4 * j + 6;
            for (int l2 = lbeg; l2 < lend; ++l2) sum += M[w2 * 64 + l2][idx];
            if (j >= 1) {
                int l2b = (j == 1) ? 0 : 4 * (j - 1) + 2;
                int l2e = 4 * (j - 1) + 6;
                for (int l2 = l2b; l2 < l2e; ++l2) sum += M[w2 * 64 + l2][6 + idx];
            }
        }
        xp16o[(size_t)bc * 256 + t] = sum;
    }
    // pool16: thread t -> (i = t>>4, j = t&15)
    {
        int i = t >> 4, j = t & 15;
        int w2 = i >> 2, slot = i & 3;
        float sum = M[w2 * 64 + 4 * j][26 + slot] + M[w2 * 64 + 4 * j + 1][26 + slot] +
                    M[w2 * 64 + 4 * j + 2][26 + slot] + M[w2 * 64 + 4 * j + 3][26 + slot];
        pool16[(size_t)bc * 256 + t] = sum * (1.f / 256.f);
    }
    // xproj8: threads 0..63 -> (i8 = t>>3, j8 = t&7)
    if (t < 64) {
        int i8 = t >> 3, j8 = t & 7;
        float sum = 0.f;
        for (int w2 = 0; w2 < 4; ++w2) {
            int idx = i8 - 2 * w2 + 1;
            if (idx < 0 || idx > 3) continue;
            int lbeg = (j8 == 0) ? 0 : 8 * j8 + 4;
            int lend = (j8 == 7) ? 64 : 8 * j8 + 12;
            for (int l2 = lbeg; l2 < lend; ++l2) sum += M[w2 * 64 + l2][12 + idx];
            if (j8 >= 1) {
                int l2b = (j8 == 1) ? 0 : 8 * (j8 - 1) + 4;
                int l2e = 8 * (j8 - 1) + 12;
                for (int l2 = l2b; l2 < l2e; ++l2) sum += M[w2 * 64 + l2][16 + idx];
            }
        }
        xp8o[(size_t)bc * 64 + t] = sum;
    }
    // xproj4: threads 64..79 -> (i4, j4)
    else if (t < 80) {
        int e = t - 64;
        int i4 = e >> 2, j4 = e & 3;
        float sum = 0.f;
        for (int w2 = 0; w2 < 4; ++w2) {
            int idx = i4 - w2 + 1;
            if (idx < 0 || idx > 2) continue;
            int lbeg = (j4 == 0) ? 0 : 16 * j4 + 8;
            int lend = (j4 == 3) ? 64 : 16 * j4 + 24;
            for (int l2 = lbeg; l2 < lend; ++l2) sum += M[w2 * 64 + l2][20 + idx];
            if (j4 >= 1) {
                int l2b = (j4 == 1) ? 0 : 16 * (j4 - 1) + 8;
                int l2e = 16 * (j4 - 1) + 24;
                for (int l2 = l2b; l2 < l2e; ++l2) sum += M[w2 * 64 + l2][23 + idx];
            }
        }
        xp4o[(size_t)bc * 16 + e] = sum;
    }
    // sx: wave 2 (threads 128..191)
    if (t >= 128 && t < 192) {
        int lane = t - 128;
        float s1 = M[lane][30] + M[64 + lane][30] + M[128 + lane][30] + M[192 + lane][30];
        float s2 = M[lane][31] + M[64 + lane][31] + M[128 + lane][31] + M[192 + lane][31];
#pragma unroll
        for (int off = 1; off < 64; off <<= 1) {
            s1 += __shfl_xor(s1, off);
            s2 += __shfl_xor(s2, off);
        }
        if (lane == 0) { sx[bc * 2] = s1; sx[bc * 2 + 1] = s2; }
    }
}

// ---------------------------------------------------------------------------
// K2: per (b, scale, site): pooled vec -> qkv -> attention -> out ->
// channel-mix with fusion_w slice -> y_s[b,o,site]. (unchanged, validated)
// ---------------------------------------------------------------------------
__global__ __launch_bounds__(256) void site_kernel(
    const float* __restrict__ pool16,
    const float* __restrict__ cw0, const float* __restrict__ cw1,
    const float* __restrict__ cw2,
    const float* __restrict__ sw0, const float* __restrict__ sw1,
    const float* __restrict__ sw2,
    const float* __restrict__ fusion_w,
    float* __restrict__ y4, float* __restrict__ y8, float* __restrict__ y16) {

    __shared__ float P[256];
    __shared__ float Wm[961];
    __shared__ float QKV[279];
    __shared__ float QW[93];
    __shared__ float A[9];
    __shared__ float OUTV[93];

    int t = threadIdx.x;
    int blk = blockIdx.x;
    int b = blk / 336;
    int r = blk % 336;

    int s, site, foff;
    const float* cw; const float* sw; float* yout;
    if (r < 256)      { s = 16; site = r;       cw = cw2; sw = sw2; foff = 186; yout = y16; }
    else if (r < 320) { s = 8;  site = r - 256; cw = cw1; sw = sw1; foff = 93;  yout = y8;  }
    else              { s = 4;  site = r - 320; cw = cw0; sw = sw0; foff = 0;   yout = y4;  }
    int i = site / s, j = site % s;

    for (int idx = t; idx < 961; idx += 256) Wm[idx] = sw[idx];

    {
        int f = 16 / s;
        float acc = 0.f;
        int base = (b * 256 + t) * 256;
        for (int ii = 0; ii < f; ++ii)
            for (int jj = 0; jj < f; ++jj)
                acc += pool16[base + (i * f + ii) * 16 + (j * f + jj)];
        P[t] = acc / (float)(f * f);
    }
    __syncthreads();

    for (int o = t; o < 279; o += 256) {
        const float4* wrow = (const float4*)(cw + o * 256);
        float acc = 0.f;
#pragma unroll 8
        for (int c4 = 0; c4 < 64; ++c4) {
            float4 wv = wrow[c4];
            acc += wv.x * P[c4 * 4] + wv.y * P[c4 * 4 + 1] +
                   wv.z * P[c4 * 4 + 2] + wv.w * P[c4 * 4 + 3];
        }
        QKV[o] = acc;
    }
    __syncthreads();

    if (t < 93) {
        int g = t / 31, m = t % 31;
        float acc = 0.f;
        for (int n = 0; n < 31; ++n) acc += QKV[g * 31 + n] * Wm[n * 31 + m];
        QW[t] = acc;
    }
    __syncthreads();
    if (t < 9) {
        int g = t / 3, h = t % 3;
        float acc = 0.f;
        for (int m = 0; m < 31; ++m) acc += QW[g * 31 + m] * QKV[93 + h * 31 + m];
        A[t] = acc * 0.57735026918962576f;
    }
    __syncthreads();
    if (t < 3) {
        float a0 = A[t * 3], a1 = A[t * 3 + 1], a2 = A[t * 3 + 2];
        float mx = fmaxf(a0, fmaxf(a1, a2));
        float e0 = expf(a0 - mx), e1 = expf(a1 - mx), e2 = expf(a2 - mx);
        float inv = 1.0f / (e0 + e1 + e2);
        A[t * 3] = e0 * inv; A[t * 3 + 1] = e1 * inv; A[t * 3 + 2] = e2 * inv;
    }
    __syncthreads();
    if (t < 93) {
        int g = t / 31, n = t % 31;
        OUTV[t] = A[g * 3] * QKV[186 + n] + A[g * 3 + 1] * QKV[186 + 31 + n] +
                  A[g * 3 + 2] * QKV[186 + 62 + n];
    }
    __syncthreads();
    {
        const float* fr = fusion_w + t * 279 + foff;
        float acc = 0.f;
#pragma unroll 31
        for (int c = 0; c < 93; ++c) acc += fr[c] * OUTV[c];
        yout[(size_t)(b * 256 + t) * (s * s) + site] = acc;
    }
}

// ---------------------------------------------------------------------------
// K3: GroupNorm stats WITHOUT touching x. (unchanged, validated)
// ---------------------------------------------------------------------------
__global__ __launch_bounds__(256) void groupstats_kernel(
    const float* __restrict__ y4, const float* __restrict__ y8,
    const float* __restrict__ y16,
    const float* __restrict__ xp4, const float* __restrict__ xp8,
    const float* __restrict__ xp16,
    const float* __restrict__ sx, const float* __restrict__ fusion_b,
    float* __restrict__ stats_g) {

    __shared__ float G1616[256], G168[128], G164[64], G88[64], G84[32], G44[16];
    __shared__ float cs[28];
    __shared__ float ybuf[336], xbuf[336];
    __shared__ float Tm[256];
    __shared__ float red[8];

    int t = threadIdx.x;
    int bg = blockIdx.x;
    int b = bg >> 5, g = bg & 31;

    for (int e = t; e < 588; e += 256) {
        if (e >= 560) {
            int q = e - 560; int sC, iC;
            if (q < 16) { sC = 16; iC = q; }
            else if (q < 24) { sC = 8; iC = q - 16; }
            else { sC = 4; iC = q - 24; }
            int R = 256 / sC;
            int lo = max(0, R * iC - R / 2), hi = min(256, R * iC + (3 * R) / 2);
            float Rinv = 1.f / (float)R, smax = (float)(sC - 1);
            float a = 0.f;
            for (int h = lo; h < hi; ++h) {
                float src = fminf(fmaxf(((float)h + 0.5f) * Rinv - 0.5f, 0.f), smax);
                int lq = (int)src; float fr = src - (float)lq;
                a += (iC == lq) ? (1.f - fr) : ((iC == lq + 1) ? fr : 0.f);
            }
            cs[q] = a;
            continue;
        }
        int sA, sB, iA, iB; float* dst; int off;
        if (e < 256)      { sA = 16; sB = 16; iA = e >> 4; iB = e & 15; dst = G1616; off = e; }
        else if (e < 384) { int q = e - 256; sA = 16; sB = 8; iA = q >> 3; iB = q & 7; dst = G168; off = q; }
        else if (e < 448) { int q = e - 384; sA = 16; sB = 4; iA = q >> 2; iB = q & 3; dst = G164; off = q; }
        else if (e < 512) { int q = e - 448; sA = 8;  sB = 8; iA = q >> 3; iB = q & 7; dst = G88;  off = q; }
        else if (e < 544) { int q = e - 512; sA = 8;  sB = 4; iA = q >> 2; iB = q & 3; dst = G84;  off = q; }
        else              { int q = e - 544; sA = 4;  sB = 4; iA = q >> 2; iB = q & 3; dst = G44;  off = q; }
        int RA = 256 / sA, RB = 256 / sB;
        int lo = max(max(0, RA * iA - RA / 2), RB * iB - RB / 2);
        int hi = min(min(256, RA * iA + (3 * RA) / 2), RB * iB + (3 * RB) / 2);
        float RAi = 1.f / (float)RA, RBi = 1.f / (float)RB;
        float smA = (float)(sA - 1), smB = (float)(sB - 1);
        float a = 0.f;
        for (int h = lo; h < hi; ++h) {
            float sa = fminf(fmaxf(((float)h + 0.5f) * RAi - 0.5f, 0.f), smA);
            int la = (int)sa; float fa = sa - (float)la;
            float wa = (iA == la) ? (1.f - fa) : ((iA == la + 1) ? fa : 0.f);
            float sb = fminf(fmaxf(((float)h + 0.5f) * RBi - 0.5f, 0.f), smB);
            int lb = (int)sb; float fb_ = sb - (float)lb;
            float wb = (iB == lb) ? (1.f - fb_) : ((iB == lb + 1) ? fb_ : 0.f);
            a += wa * wb;
        }
        dst[off] = a;
    }
    __syncthreads();

    double gS1 = 0.0, gS2 = 0.0;

    for (int c8 = 0; c8 < 8; ++c8) {
        int c = g * 8 + c8;
        size_t bc = (size_t)(b * 256 + c);
        ybuf[t] = y16[bc * 256 + t];
        xbuf[t] = xp16[bc * 256 + t];
        if (t < 64) { ybuf[256 + t] = y8[bc * 64 + t]; xbuf[256 + t] = xp8[bc * 64 + t]; }
        else if (t < 80) { ybuf[256 + t] = y4[bc * 16 + (t - 64)]; xbuf[256 + t] = xp4[bc * 16 + (t - 64)]; }
        __syncthreads();

        float pu = 0.f, pv = 0.f;
        for (int e = t; e < 336; e += 256) {
            float yv = ybuf[e];
            pv += 2.f * yv * xbuf[e];
            int ci, cj;
            if (e < 256)      { ci = e >> 4;               cj = e & 15; }
            else if (e < 320) { ci = 16 + ((e - 256) >> 3); cj = 16 + ((e - 256) & 7); }
            else              { ci = 24 + ((e - 320) >> 2); cj = 24 + ((e - 320) & 3); }
            pu += yv * cs[ci] * cs[cj];
        }

        for (int p = 0; p < 6; ++p) {
            const float* Gp; int sA, sB, yAoff, yBoff; float factor;
            switch (p) {
                case 0: Gp = G1616; sA = 16; sB = 16; yAoff = 0;   yBoff = 0;   factor = 1.f; break;
                case 1: Gp = G168;  sA = 16; sB = 8;  yAoff = 0;   yBoff = 256; factor = 2.f; break;
                case 2: Gp = G164;  sA = 16; sB = 4;  yAoff = 0;   yBoff = 320; factor = 2.f; break;
                case 3: Gp = G88;   sA = 8;  sB = 8;  yAoff = 256; yBoff = 256; factor = 1.f; break;
                case 4: Gp = G84;   sA = 8;  sB = 4;  yAoff = 256; yBoff = 320; factor = 2.f; break;
                default:Gp = G44;   sA = 4;  sB = 4;  yAoff = 320; yBoff = 320; factor = 1.f; break;
            }
            __syncthreads();
            int nT = sB * sA;
            if (t < nT) {
                int iB = t / sA, jA = t - iB * sA;
                float a = 0.f;
                for (int jB = 0; jB < sB; ++jB)
                    a += Gp[jA * sB + jB] * ybuf[yBoff + iB * sB + jB];
                Tm[t] = a;
            }
            __syncthreads();
            int nB = sA * sA;
            if (t < nB) {
                int iA = t / sA, jA = t - iA * sA;
                float a = 0.f;
                for (int iB = 0; iB < sB; ++iB)
                    a += Gp[iA * sB + iB] * Tm[iB * sA + jA];
                pv += factor * ybuf[yAoff + t] * a;
            }
        }

#pragma unroll
        for (int off = 1; off < 64; off <<= 1) {
            pu += __shfl_xor(pu, off);
            pv += __shfl_xor(pv, off);
        }
        __syncthreads();
        if ((t & 63) == 0) { red[(t >> 6) * 2] = pu; red[(t >> 6) * 2 + 1] = pv; }
        __syncthreads();
        if (t == 0) {
            float puT = red[0] + red[2] + red[4] + red[6];
            float pvT = red[1] + red[3] + red[5] + red[7];
            float fb = fusion_b[c];
            float s1 = sx[(b * 256 + c) * 2], s2 = sx[(b * 256 + c) * 2 + 1];
            double S1 = (double)s1 + 65536.0 * (double)fb + (double)puT;
            double S2 = (double)s2 + 2.0 * (double)fb * (double)s1 +
                        65536.0 * (double)fb * (double)fb +
                        2.0 * (double)fb * (double)puT + (double)pvT;
            gS1 += S1; gS2 += S2;
        }
        __syncthreads();
    }

    if (t == 0) {
        double mean = gS1 / 524288.0;
        double var  = gS2 / 524288.0 - mean * mean;
        stats_g[bg * 2] = (float)mean;
        stats_g[bg * 2 + 1] = (float)(1.0 / sqrt(var + 1e-5));
    }
}

// ---------------------------------------------------------------------------
// K4: final pass — recompute f via LDS-blended interp, normalize, write.
// (unchanged, validated)
// ---------------------------------------------------------------------------
__global__ __launch_bounds__(256) void write_kernel(
    const float* __restrict__ x,
    const float* __restrict__ ws_y4, const float* __restrict__ ws_y8,
    const float* __restrict__ ws_y16,
    const float* __restrict__ fusion_b,
    const float* __restrict__ gn_w, const float* __restrict__ gn_b,
    const float* __restrict__ stats_g,
    float* __restrict__ out) {

    __shared__ float ly16[256], ly8[64], ly4[16];
    __shared__ float2 rbd16[16][16];
    __shared__ float2 rbd8[16][8];
    __shared__ float2 rbd4[16][4];

    int blk = blockIdx.x;
    int hblk = blk & 15;
    int c = (blk >> 4) & 255;
    int b = blk >> 12;
    int t = threadIdx.x;

    ly16[t] = ws_y16[(size_t)(b * 256 + c) * 256 + t];
    if (t < 64) ly8[t] = ws_y8[(size_t)(b * 256 + c) * 64 + t];
    if (t < 16) ly4[t] = ws_y4[(size_t)(b * 256 + c) * 16 + t];
    __syncthreads();

    for (int idx = t; idx < 448; idx += 256) {
        int r = idx / 28;
        int q = idx - r * 28;
        int h = hblk * 16 + r;
        if (q < 16) {
            float src = (h + 0.5f) * 0.0625f - 0.5f;
            src = fminf(fmaxf(src, 0.f), 15.f);
            int lo = (int)src; float wf = src - lo; int hi = min(lo + 1, 15);
            float rb = (1.f - wf) * ly16[lo * 16 + q] + wf * ly16[hi * 16 + q];
            rbd16[r][q].x = rb;
            if (q > 0) rbd16[r][q - 1].y = rb;
            if (q == 15) rbd16[r][15].y = rb;
        } else if (q < 24) {
            int jj = q - 16;
            float src = (h + 0.5f) * 0.03125f - 0.5f;
            src = fminf(fmaxf(src, 0.f), 7.f);
            int lo = (int)src; float wf = src - lo; int hi = min(lo + 1, 7);
            float rb = (1.f - wf) * ly8[lo * 8 + jj] + wf * ly8[hi * 8 + jj];
            rbd8[r][jj].x = rb;
            if (jj > 0) rbd8[r][jj - 1].y = rb;
            if (jj == 7) rbd8[r][7].y = rb;
        } else {
            int jj = q - 24;
            float src = (h + 0.5f) * 0.015625f - 0.5f;
            src = fminf(fmaxf(src, 0.f), 3.f);
            int lo = (int)src; float wf = src - lo; int hi = min(lo + 1, 3);
            float rb = (1.f - wf) * ly4[lo * 4 + jj] + wf * ly4[hi * 4 + jj];
            rbd4[r][jj].x = rb;
            if (jj > 0) rbd4[r][jj - 1].y = rb;
            if (jj == 3) rbd4[r][3].y = rb;
        }
    }
    __syncthreads();

    int w4 = t & 63;
    int wg = t >> 6;
    int w0 = w4 * 4;

    int jlo16[4], jlo8[4], jlo4[4];
    float ww16[4], ww8[4], ww4[4];
#pragma unroll
    for (int p = 0; p < 4; ++p) {
        int w = w0 + p;
        float s16 = fminf(fmaxf((w + 0.5f) * 0.0625f - 0.5f, 0.f), 15.f);
        jlo16[p] = (int)s16; ww16[p] = s16 - jlo16[p];
        float s8 = fminf(fmaxf((w + 0.5f) * 0.03125f - 0.5f, 0.f), 7.f);
        jlo8[p] = (int)s8; ww8[p] = s8 - jlo8[p];
        float s4 = fminf(fmaxf((w + 0.5f) * 0.015625f - 0.5f, 0.f), 3.f);
        jlo4[p] = (int)s4; ww4[p] = s4 - jlo4[p];
    }

    float fb_c = fusion_b[c];
    int gidx = c >> 3;
    float mean = stats_g[(b * 32 + gidx) * 2];
    float rstd = stats_g[(b * 32 + gidx) * 2 + 1];
    float gwc = gn_w[c], gbc = gn_b[c];

    const float4* xp = (const float4*)(x + (size_t)(b * 256 + c) * (H * Wd));
    float4* op = (float4*)(out + (size_t)(b * 256 + c) * (H * Wd));

#pragma unroll
    for (int it = 0; it < 4; ++it) {
        int r = it * 4 + wg;
        int idx4 = (hblk * 16 + r) * 64 + w4;
        float4 xv = xp[idx4];
        float res[4];
        float px[4] = {xv.x, xv.y, xv.z, xv.w};
#pragma unroll
        for (int p = 0; p < 4; ++p) {
            float f = fb_c;
            float2 v16 = rbd16[r][jlo16[p]];
            f += (1.f - ww16[p]) * v16.x + ww16[p] * v16.y;
            float2 v8 = rbd8[r][jlo8[p]];
            f += (1.f - ww8[p]) * v8.x + ww8[p] * v8.y;
            float2 v4 = rbd4[r][jlo4[p]];
            f += (1.f - ww4[p]) * v4.x + ww4[p] * v4.y;
            float tv = px[p] + f;
            res[p] = (tv - mean) * rstd * gwc + gbc;
        }
        op[idx4] = make_float4(res[0], res[1], res[2], res[3]);
    }
}

// ---------------------------------------------------------------------------
extern "C" void kernel_launch(void* const* d_in, const int* in_sizes, int n_in,
                              void* d_out, int out_size, void* d_ws, size_t ws_size,
                              hipStream_t stream) {
    const float* x   = (const float*)d_in[0];
    const float* cw0 = (const float*)d_in[1];
    const float* cw1 = (const float*)d_in[2];
    const float* cw2 = (const float*)d_in[3];
    const float* sw0 = (const float*)d_in[4];
    const float* sw1 = (const float*)d_in[5];
    const float* sw2 = (const float*)d_in[6];
    const float* fw  = (const float*)d_in[7];
    const float* fb  = (const float*)d_in[8];
    const float* gw  = (const float*)d_in[9];
    const float* gb  = (const float*)d_in[10];
    float* out = (float*)d_out;

    float* ws     = (float*)d_ws;
    float* pool16 = ws;                    // 262144
    float* y4     = pool16 + 262144;       // 16384
    float* y8     = y4 + 16384;            // 65536
    float* y16    = y8 + 65536;            // 262144
    float* xp16   = y16 + 262144;          // 262144
    float* xp8    = xp16 + 262144;         // 65536
    float* xp4    = xp8 + 65536;           // 16384
    float* sx     = xp4 + 16384;           // 2048
    float* statsg = sx + 2048;             // 256

    poolproj_kernel<<<B * C, 256, 0, stream>>>(x, pool16, xp16, xp8, xp4, sx);
    site_kernel<<<B * 336, 256, 0, stream>>>(pool16, cw0, cw1, cw2,
                                             sw0, sw1, sw2, fw, y4, y8, y16);
    groupstats_kernel<<<B * 32, 256, 0, stream>>>(y4, y8, y16, xp4, xp8, xp16,
                                                  sx, fb, statsg);
    write_kernel<<<B * C * 16, 256, 0, stream>>>(x, y4, y8, y16, fb, gw, gb,
                                                 statsg, out);
}